// Round 6
// baseline (785.542 us; speedup 1.0000x reference)
//
#include <hip/hip_runtime.h>
#include <hip/hip_bf16.h>

using f32x4  = __attribute__((ext_vector_type(4))) float;
using u32x4  = __attribute__((ext_vector_type(4))) unsigned int;
using bf16x8 = __attribute__((ext_vector_type(8))) short;

__device__ __forceinline__ ushort f2bf(float x) {
    union { __hip_bfloat16 h; ushort u; } cv;
    cv.h = __float2bfloat16(x);
    return cv.u;
}
__device__ __forceinline__ unsigned pk2(float lo, float hi) {
    return (unsigned)f2bf(lo) | ((unsigned)f2bf(hi) << 16);
}
__device__ __forceinline__ float sigmoidf_(float x) { return 1.f / (1.f + expf(-x)); }

// ---------------------------------------------------------------------------
// GEMM: C[M,N] = A * B(bf16,[K,N]) (+bias, relu, bf16/f32 out)
// A: bf16 (A_BF16), f32 (NSUM==0), or sum of NSUM f32 split-K partial chunks
//    spaced pStride apart (fused reduce).
// BM=128, BN=64, BK=32. 256 threads = 4 waves (2x2), wave tile 64x32.
// SPLIT: blockIdx.z selects K-chunk, writes f32 partial at Cf + z*M*N.
// ---------------------------------------------------------------------------
template<int NSUM, bool A_BF16, bool SPLIT, bool RELU, bool BF16_OUT, bool HAS_BIAS>
__global__ __launch_bounds__(256)
void gemm_kernel(const void* __restrict__ Avoid, const ushort* __restrict__ B,
                 const float* __restrict__ bias, float* __restrict__ Cf,
                 ushort* __restrict__ Cb, int M, int N, int K, int ldc,
                 int kPerChunk, long pStride)
{
    __shared__ ushort As[128 * 40];
    __shared__ ushort Bs[64 * 40];
    const int tid  = threadIdx.x;
    const int lane = tid & 63;
    const int wid  = tid >> 6;
    const int wr   = wid >> 1, wc = wid & 1;
    const int g    = lane >> 4, lr = lane & 15;
    const long m0  = (long)blockIdx.x * 128;
    const int  n0  = blockIdx.y * 64;

    int kbeg = 0, kend = K;
    if (SPLIT) { kbeg = blockIdx.z * kPerChunk; kend = kbeg + kPerChunk; if (kend > K) kend = K; }

    const int bkr = tid & 31;   // B k-row within tile
    const int bcb = tid >> 5;   // B col-octet

    const float*  Af = (const float*)Avoid;
    const ushort* Ab = (const ushort*)Avoid;

    f32x4 pa[4];
    u32x4 pab[2];
    u32x4 pb;

    auto loadT = [&](int k0) {
        if (A_BF16) {
#pragma unroll
            for (int i = 0; i < 2; i++) {
                int s = tid + 256 * i; int row = s >> 2, c8 = s & 3;
                pab[i] = *(const u32x4*)(Ab + (m0 + row) * (long)K + k0 + c8 * 8);
            }
        } else {
#pragma unroll
            for (int i = 0; i < 4; i++) {
                int s = tid + 256 * i; int row = s >> 3, c4 = s & 7;
                const float* base = Af + (m0 + row) * (long)K + k0 + c4 * 4;
                f32x4 v = *(const f32x4*)base;
                if (NSUM > 0) {
#pragma unroll
                    for (int z = 1; z < NSUM; z++) v += *(const f32x4*)(base + z * pStride);
                }
                pa[i] = v;
            }
        }
        pb = *(const u32x4*)(B + (long)(k0 + bkr) * N + n0 + bcb * 8);
    };
    auto storeT = [&]() {
        if (A_BF16) {
#pragma unroll
            for (int i = 0; i < 2; i++) {
                int s = tid + 256 * i; int row = s >> 2, c8 = s & 3;
                *(u32x4*)(&As[row * 40 + c8 * 8]) = pab[i];
            }
        } else {
#pragma unroll
            for (int i = 0; i < 4; i++) {
                int s = tid + 256 * i; int row = s >> 3, c4 = s & 7;
                ushort4 w;
                w.x = f2bf(pa[i].x); w.y = f2bf(pa[i].y);
                w.z = f2bf(pa[i].z); w.w = f2bf(pa[i].w);
                *(ushort4*)(&As[row * 40 + c4 * 4]) = w;
            }
        }
        const ushort* p8 = (const ushort*)&pb;
#pragma unroll
        for (int j = 0; j < 8; j++) Bs[(bcb * 8 + j) * 40 + bkr] = p8[j];
    };

    f32x4 acc[4][2] = {};

    const int nk = (kend - kbeg) >> 5;
    loadT(kbeg);
    for (int t = 0; t < nk; ++t) {
        storeT();
        __syncthreads();
        if (t + 1 < nk) loadT(kbeg + ((t + 1) << 5));
        bf16x8 af[4], bfr[2];
#pragma unroll
        for (int fm = 0; fm < 4; fm++)
            af[fm] = *(const bf16x8*)(&As[(wr * 64 + fm * 16 + lr) * 40 + g * 8]);
#pragma unroll
        for (int fn = 0; fn < 2; fn++)
            bfr[fn] = *(const bf16x8*)(&Bs[(wc * 32 + fn * 16 + lr) * 40 + g * 8]);
#pragma unroll
        for (int fm = 0; fm < 4; fm++)
#pragma unroll
            for (int fn = 0; fn < 2; fn++)
                acc[fm][fn] = __builtin_amdgcn_mfma_f32_16x16x32_bf16(af[fm], bfr[fn], acc[fm][fn], 0, 0, 0);
        __syncthreads();
    }

    if (SPLIT) {
        float* P = Cf + (long)blockIdx.z * M * N;
#pragma unroll
        for (int fm = 0; fm < 4; fm++)
#pragma unroll
            for (int fn = 0; fn < 2; fn++)
#pragma unroll
                for (int rr = 0; rr < 4; rr++) {
                    long row = m0 + wr * 64 + fm * 16 + g * 4 + rr;
                    int  col = n0 + wc * 32 + fn * 16 + lr;
                    P[row * N + col] = acc[fm][fn][rr];
                }
    } else {
#pragma unroll
        for (int fm = 0; fm < 4; fm++)
#pragma unroll
            for (int fn = 0; fn < 2; fn++)
#pragma unroll
                for (int rr = 0; rr < 4; rr++) {
                    long row = m0 + wr * 64 + fm * 16 + g * 4 + rr;
                    int  col = n0 + wc * 32 + fn * 16 + lr;
                    float v = acc[fm][fn][rr];
                    if (HAS_BIAS) v += bias[col];
                    if (RELU) v = fmaxf(v, 0.f);
                    if (BF16_OUT) Cb[row * ldc + col] = f2bf(v);
                    else          Cf[row * ldc + col] = v;
                }
    }
}

// prep: A->bf16, X_n->bf16, W1/W2 transposes, Zt1 = X_e@W1h^T + b (bf16),
// zero stats. One launch, 10881 blocks.
__global__ __launch_bounds__(256) void prep_k(const float* __restrict__ A, ushort* __restrict__ Abf,
                                              const float* __restrict__ Xn, ushort* __restrict__ Xnb,
                                              const float* __restrict__ W1, ushort* __restrict__ W1t,
                                              const float* __restrict__ W2, ushort* __restrict__ W2t,
                                              const float* __restrict__ Xe, const float* __restrict__ Wh,
                                              const float* __restrict__ hb, ushort* __restrict__ Zt1,
                                              float* __restrict__ stats)
{
    int b = blockIdx.x, t = threadIdx.x;
    if (b < 8192) {                       // A: 16.78M elems, 8/thread
        long j = (long)b * 256 + t;
        f32x4 v0 = ((const f32x4*)A)[2 * j];
        f32x4 v1 = ((const f32x4*)A)[2 * j + 1];
        u32x4 w;
        w.x = pk2(v0.x, v0.y); w.y = pk2(v0.z, v0.w);
        w.z = pk2(v1.x, v1.y); w.w = pk2(v1.z, v1.w);
        ((u32x4*)Abf)[j] = w;
    } else if (b < 8448) {                // X_n
        long j = (long)(b - 8192) * 256 + t;
        f32x4 v0 = ((const f32x4*)Xn)[2 * j];
        f32x4 v1 = ((const f32x4*)Xn)[2 * j + 1];
        u32x4 w;
        w.x = pk2(v0.x, v0.y); w.y = pk2(v0.z, v0.w);
        w.z = pk2(v1.x, v1.y); w.w = pk2(v1.z, v1.w);
        ((u32x4*)Xnb)[j] = w;
    } else if (b < 8576) {                // W1 [256,128] -> T [128,256]
        int j = (b - 8448) * 256 + t;
        int i = j >> 8, o = j & 255;
        W1t[j] = f2bf(W1[o * 128 + i]);
    } else if (b < 8832) {                // W2 [256,256] -> T [256,256]
        int j = (b - 8576) * 256 + t;
        int i = j >> 8, o = j & 255;
        W2t[j] = f2bf(W2[o * 256 + i]);
    } else if (b < 10880) {               // Zt1[e][o] = X_e[e,:].Wh[o,:] + hb[o]
        int row = (b - 8832) * 4 + (t >> 6);
        int o   = t & 63;
        const float* xr = Xe + (long)row * 64;
        const float* wr = Wh + (long)o * 64;
        float acc = hb[o];
#pragma unroll 8
        for (int i = 0; i < 64; i++) acc += xr[i] * wr[i];
        Zt1[(long)row * 64 + o] = f2bf(acc);
    } else {
        if (t < 192) stats[t] = 0.f;      // gsum[64], gsq[64], S5[5]
    }
}

// fused: Zc1 = sum of 8 partials; column sum/sumsq stats. grid 256 x 256
__global__ __launch_bounds__(256) void bnred_k(const float* __restrict__ P,
                                               float* __restrict__ Zc,
                                               float* __restrict__ gsum, float* __restrict__ gsq)
{
    const long MN = 8192 * 64;
    int b = blockIdx.x, t = threadIdx.x;
    int c = t & 63, rg = t >> 6;
    float sx = 0.f, sq = 0.f;
    int base = b * 32 + rg;
#pragma unroll 4
    for (int i = 0; i < 8; i++) {
        long idx = (long)(base + 4 * i) * 64 + c;
        float x = 0.f;
#pragma unroll
        for (int z = 0; z < 8; z++) x += P[idx + z * MN];
        Zc[idx] = x;
        sx += x; sq += x * x;
    }
    __shared__ float ls[256], lq[256];
    ls[t] = sx; lq[t] = sq;
    __syncthreads();
    if (t < 64) {
        float a = ls[t] + ls[t + 64] + ls[t + 128] + ls[t + 192];
        float q = lq[t] + lq[t + 64] + lq[t + 128] + lq[t + 192];
        atomicAdd(&gsum[t], a);
        atomicAdd(&gsq[t], q);
    }
}

// Z1[row] = max_c relu(bn(Zc1[row,c])); wave per row, grid 2048 x 256
__global__ __launch_bounds__(256) void z1_k(const float* __restrict__ Zc,
                                            const float* __restrict__ gsum, const float* __restrict__ gsq,
                                            const float* __restrict__ g, const float* __restrict__ b,
                                            float* __restrict__ Z1)
{
    int w = threadIdx.x >> 6, lane = threadIdx.x & 63;
    int row = blockIdx.x * 4 + w;
    const float inv = 1.f / 8192.f;
    float m = gsum[lane] * inv;
    float v = gsq[lane] * inv - m * m;
    float x = Zc[row * 64 + lane];
    float y = fmaxf(g[lane] * (x - m) * rsqrtf(v + 1e-5f) + b[lane], 0.f);
#pragma unroll
    for (int o = 32; o > 0; o >>= 1) y = fmaxf(y, __shfl_xor(y, o));
    if (lane == 0) Z1[row] = y;
}

// s[i]=L1[i,:].Z1 ; r[i]=rowsum(L1[i,:]); block per row, grid 8192 x 256.
// Fused: atomically accumulates the 5 moments of (s,r) into S5.
__global__ __launch_bounds__(256) void pass2_k(const float* __restrict__ L1, const float* __restrict__ Z1,
                                               float* __restrict__ s, float* __restrict__ r,
                                               float* __restrict__ S5)
{
    int row = blockIdx.x, t = threadIdx.x;
    int l = t & 63, w = t >> 6;
    const f32x4* rp = (const f32x4*)(L1 + (long)row * 8192);
    const f32x4* z4 = (const f32x4*)Z1;
    float as = 0.f, ar = 0.f;
#pragma unroll 4
    for (int k = 0; k < 8; k++) {
        f32x4 v = rp[t + 256 * k];
        f32x4 z = z4[t + 256 * k];
        as += v.x * z.x + v.y * z.y + v.z * z.z + v.w * z.w;
        ar += v.x + v.y + v.z + v.w;
    }
#pragma unroll
    for (int o = 32; o > 0; o >>= 1) { as += __shfl_xor(as, o); ar += __shfl_xor(ar, o); }
    __shared__ float sw[4], rw[4];
    if (l == 0) { sw[w] = as; rw[w] = ar; }
    __syncthreads();
    if (t == 0) {
        float S = sw[0] + sw[1] + sw[2] + sw[3];
        float R = rw[0] + rw[1] + rw[2] + rw[3];
        s[row] = S; r[row] = R;
        atomicAdd(&S5[0], S);     atomicAdd(&S5[1], R);
        atomicAdd(&S5[2], S * S); atomicAdd(&S5[3], R * R);
        atomicAdd(&S5[4], S * R);
    }
}

// Z2 + edge_prob; wave per row; grid 2048 x 256
__global__ __launch_bounds__(256) void z2_edge_k(const float* __restrict__ s, const float* __restrict__ r,
                                                 const float* __restrict__ S,
                                                 const float* __restrict__ W2, const float* __restrict__ b2,
                                                 const float* __restrict__ g2, const float* __restrict__ bb2,
                                                 const float* __restrict__ eW, const float* __restrict__ eb,
                                                 const float* __restrict__ Z1,
                                                 float* __restrict__ Z2, float* __restrict__ edge_out)
{
    int w = threadIdx.x >> 6, lane = threadIdx.x & 63;
    int row = blockIdx.x * 4 + w;
    const float inv = 1.f / 8192.f;
    float ms = S[0] * inv, mr = S[1] * inv;
    float vs = S[2] * inv - ms * ms;
    float vr = S[3] * inv - mr * mr;
    float cv = S[4] * inv - ms * mr;
    float w2 = W2[lane], bz = b2[lane];
    float mc = w2 * ms + bz * mr;
    float vc = w2 * w2 * vs + 2.f * w2 * bz * cv + bz * bz * vr;
    float x  = w2 * s[row] + bz * r[row];
    float y  = fmaxf(g2[lane] * (x - mc) * rsqrtf(vc + 1e-5f) + bb2[lane], 0.f);
#pragma unroll
    for (int o = 32; o > 0; o >>= 1) y = fmaxf(y, __shfl_xor(y, o));
    if (lane == 0) {
        Z2[row] = y;
        float e = Z1[row] * eW[0] + y * eW[1] + eb[0];
        edge_out[row] = sigmoidf_(e);
    }
}

// H_e (B1@[Z1 Z2]) into hcat cols 256/257 + node head; block per row, grid 4096
__global__ __launch_bounds__(256) void he_node_k(const float* __restrict__ B1, const float* __restrict__ Z1,
                                                 const float* __restrict__ Z2, float* __restrict__ hcat,
                                                 const float* __restrict__ nW, const float* __restrict__ nb,
                                                 float* __restrict__ node_out)
{
    int n = blockIdx.x, t = threadIdx.x;
    int l = t & 63, w = t >> 6;
    const f32x4* rp  = (const f32x4*)(B1 + (long)n * 8192);
    const f32x4* z1v = (const f32x4*)Z1;
    const f32x4* z2v = (const f32x4*)Z2;
    float a1 = 0.f, a2 = 0.f;
#pragma unroll 4
    for (int k = 0; k < 8; k++) {
        f32x4 v = rp[t + 256 * k];
        f32x4 p = z1v[t + 256 * k];
        f32x4 q = z2v[t + 256 * k];
        a1 += v.x * p.x + v.y * p.y + v.z * p.z + v.w * p.w;
        a2 += v.x * q.x + v.y * q.y + v.z * q.z + v.w * q.w;
    }
    float d = hcat[(long)n * 258 + t] * nW[t];
#pragma unroll
    for (int o = 32; o > 0; o >>= 1) {
        a1 += __shfl_xor(a1, o); a2 += __shfl_xor(a2, o); d += __shfl_xor(d, o);
    }
    __shared__ float s1[4], s2[4], s3[4];
    if (l == 0) { s1[w] = a1; s2[w] = a2; s3[w] = d; }
    __syncthreads();
    if (t == 0) {
        float A1 = s1[0] + s1[1] + s1[2] + s1[3];
        float A2 = s2[0] + s2[1] + s2[2] + s2[3];
        float D  = s3[0] + s3[1] + s3[2] + s3[3];
        hcat[(long)n * 258 + 256] = A1;
        hcat[(long)n * 258 + 257] = A2;
        node_out[n] = sigmoidf_(D + A1 * nW[256] + A2 * nW[257] + nb[0]);
    }
}

// hyperedge gather-mean-dot-sigmoid; wave per hyperedge; grid 256 x 256
__global__ __launch_bounds__(256) void hyper_k(const void* __restrict__ he_idx,
                                               const float* __restrict__ hcat,
                                               const float* __restrict__ hW, const float* __restrict__ hb,
                                               float* __restrict__ out)
{
    int w = threadIdx.x >> 6, lane = threadIdx.x & 63;
    int h = blockIdx.x * 4 + w;
    const unsigned int* u = (const unsigned int*)he_idx;
    unsigned int odd = u[2 * lane + 1];
    bool is64 = __all(odd == 0u);
    float acc = 0.f;
    for (int k = 0; k < 8; k++) {
        int idx;
        if (is64) idx = (int)((const long long*)he_idx)[h * 8 + k];
        else      idx = ((const int*)he_idx)[h * 8 + k];
        const float* hr = hcat + (long)idx * 258;
        for (int d = lane; d < 258; d += 64) acc += hr[d] * hW[d];
    }
    acc *= 0.125f;
#pragma unroll
    for (int o = 32; o > 0; o >>= 1) acc += __shfl_xor(acc, o);
    if (lane == 0) out[h] = sigmoidf_(acc + hb[0]);
}

// ---------------------------------------------------------------------------
extern "C" void kernel_launch(void* const* d_in, const int* in_sizes, int n_in,
                              void* d_out, int out_size, void* d_ws, size_t ws_size,
                              hipStream_t stream)
{
    const float* X_n  = (const float*)d_in[0];
    const float* X_e  = (const float*)d_in[1];
    const float* A_t  = (const float*)d_in[2];
    const float* L1   = (const float*)d_in[3];
    const float* B1   = (const float*)d_in[4];
    const float* gW1  = (const float*)d_in[5];
    const float* gb1  = (const float*)d_in[6];
    const float* gW2  = (const float*)d_in[7];
    const float* gb2  = (const float*)d_in[8];
    const float* hW1  = (const float*)d_in[9];
    const float* hb1  = (const float*)d_in[10];
    const float* bn1g = (const float*)d_in[11];
    const float* bn1b = (const float*)d_in[12];
    const float* hW2  = (const float*)d_in[13];
    const float* hb2  = (const float*)d_in[14];
    const float* bn2g = (const float*)d_in[15];
    const float* bn2b = (const float*)d_in[16];
    const float* nW   = (const float*)d_in[17];
    const float* nb   = (const float*)d_in[18];
    const float* eW   = (const float*)d_in[19];
    const float* ebb  = (const float*)d_in[20];
    const float* yW   = (const float*)d_in[21];
    const float* yb   = (const float*)d_in[22];
    const void*  he   = d_in[23];

    float* out       = (float*)d_out;
    float* out_node  = out;              // 4096
    float* out_edge  = out + 4096;       // 8192
    float* out_hyper = out + 12288;      // 1024
    float* hcat      = out + 13312;      // 4096 x 258

    size_t off = 0;
    auto alloc = [&](size_t bytes) {
        void* p = (char*)d_ws + off;
        off = (off + bytes + 255) & ~(size_t)255;
        return p;
    };
    ushort* Abf   = (ushort*)alloc((size_t)4096 * 4096 * 2);  // 33.5 MB
    ushort* Xn_bf = (ushort*)alloc(4096 * 128 * 2);
    ushort* W1t   = (ushort*)alloc(128 * 256 * 2);
    ushort* W2t   = (ushort*)alloc(256 * 256 * 2);
    ushort* Zt1   = (ushort*)alloc(8192 * 64 * 2);
    float*  Zc1   = (float*)alloc(8192 * 64 * 4);
    float*  stats = (float*)alloc(256 * 4);   // gsum[64], gsq[64], S5[5]
    float*  gsum  = stats;
    float*  gsq   = stats + 64;
    float*  S5    = stats + 128;
    float*  Z1    = (float*)alloc(8192 * 4);
    float*  Z2    = (float*)alloc(8192 * 4);
    float*  sbuf  = (float*)alloc(8192 * 4);
    float*  rbuf  = (float*)alloc(8192 * 4);
    float*  P     = (float*)alloc((size_t)8192 * 64 * 8 * 4); // split-K partials (16.8 MB)

    // 1. prep: converts + transposes + Zt1 mini-GEMM + stat zero
    prep_k<<<10881, 256, 0, stream>>>(A_t, Abf, X_n, Xn_bf, gW1, W1t, gW2, W2t,
                                      X_e, hW1, hb1, Zt1, stats);

    // 2. K1: Abf @ Xnb -> P (split 4)
    gemm_kernel<0, true, true, false, false, false><<<dim3(32, 2, 4), 256, 0, stream>>>(
        Abf, Xn_bf, nullptr, P, nullptr, 4096, 128, 4096, 128, 1024, 0);
    // 3. K2: (sum P) @ W1t + b1, relu -> H_bf  (fused reduce)
    gemm_kernel<4, false, false, true, true, true><<<dim3(32, 4, 1), 256, 0, stream>>>(
        P, W1t, gb1, nullptr, (ushort*)Zc1 /*reuse as H_bf*/, 4096, 256, 128, 256, 0,
        (long)4096 * 128);
    ushort* H_bf = (ushort*)Zc1;  // 2 MB region reused before Zc1 is live
    // 4. K3: Abf @ H_bf -> P (split 2)
    gemm_kernel<0, true, true, false, false, false><<<dim3(32, 4, 2), 256, 0, stream>>>(
        Abf, H_bf, nullptr, P, nullptr, 4096, 256, 4096, 256, 2048, 0);
    // 5. K4: (sum P) @ W2t + b2, relu -> hcat (f32, ldc 258)  (fused reduce)
    gemm_kernel<2, false, false, true, false, true><<<dim3(32, 4, 1), 256, 0, stream>>>(
        P, W2t, gb2, hcat, nullptr, 4096, 256, 256, 258, 0, (long)4096 * 256);

    // 6. K6: L1(f32) @ Zt1 -> P (split 8)
    gemm_kernel<0, false, true, false, false, false><<<dim3(64, 1, 8), 256, 0, stream>>>(
        L1, Zt1, nullptr, P, nullptr, 8192, 64, 8192, 64, 1024, 0);
    // 7. bnred: Zc1 = sum P + column stats
    bnred_k<<<256, 256, 0, stream>>>(P, Zc1, gsum, gsq);
    // 8. z1
    z1_k<<<2048, 256, 0, stream>>>(Zc1, gsum, gsq, bn1g, bn1b, Z1);
    // 9. pass2 (+ fused 5-moment stats)
    pass2_k<<<8192, 256, 0, stream>>>(L1, Z1, sbuf, rbuf, S5);
    // 10. z2 + edge head
    z2_edge_k<<<2048, 256, 0, stream>>>(sbuf, rbuf, S5, hW2, hb2, bn2g, bn2b,
                                        eW, ebb, Z1, Z2, out_edge);
    // 11. H_e + node head
    he_node_k<<<4096, 256, 0, stream>>>(B1, Z1, Z2, hcat, nW, nb, out_node);
    // 12. hyper head
    hyper_k<<<256, 256, 0, stream>>>(he, hcat, yW, yb, out_hyper);
}

// Round 7
// 303.763 us; speedup vs baseline: 2.5860x; 2.5860x over previous
//
#include <hip/hip_runtime.h>
#include <hip/hip_bf16.h>

using f32x4  = __attribute__((ext_vector_type(4))) float;
using u32x4  = __attribute__((ext_vector_type(4))) unsigned int;
using bf16x8 = __attribute__((ext_vector_type(8))) short;

__device__ __forceinline__ ushort f2bf(float x) {
    union { __hip_bfloat16 h; ushort u; } cv;
    cv.h = __float2bfloat16(x);
    return cv.u;
}
__device__ __forceinline__ unsigned pk2(float lo, float hi) {
    return (unsigned)f2bf(lo) | ((unsigned)f2bf(hi) << 16);
}
__device__ __forceinline__ float sigmoidf_(float x) { return 1.f / (1.f + expf(-x)); }

// ---------------------------------------------------------------------------
// GEMM: C[M,N] = A * B(bf16,[K,N]) (+bias, relu, bf16/f32 out)
// A: bf16 (A_BF16), f32 (NSUM==0), or sum of NSUM f32 split-K partial chunks
//    spaced pStride apart (fused reduce).
// BM=128, BN=64, BK=32. 256 threads = 4 waves (2x2), wave tile 64x32.
// SPLIT: blockIdx.z selects K-chunk, writes f32 partial at Cf + z*M*N.
// ---------------------------------------------------------------------------
template<int NSUM, bool A_BF16, bool SPLIT, bool RELU, bool BF16_OUT, bool HAS_BIAS>
__global__ __launch_bounds__(256)
void gemm_kernel(const void* __restrict__ Avoid, const ushort* __restrict__ B,
                 const float* __restrict__ bias, float* __restrict__ Cf,
                 ushort* __restrict__ Cb, int M, int N, int K, int ldc,
                 int kPerChunk, long pStride)
{
    __shared__ ushort As[128 * 40];
    __shared__ ushort Bs[64 * 40];
    const int tid  = threadIdx.x;
    const int lane = tid & 63;
    const int wid  = tid >> 6;
    const int wr   = wid >> 1, wc = wid & 1;
    const int g    = lane >> 4, lr = lane & 15;
    const long m0  = (long)blockIdx.x * 128;
    const int  n0  = blockIdx.y * 64;

    int kbeg = 0, kend = K;
    if (SPLIT) { kbeg = blockIdx.z * kPerChunk; kend = kbeg + kPerChunk; if (kend > K) kend = K; }

    const int bkr = tid & 31;   // B k-row within tile
    const int bcb = tid >> 5;   // B col-octet

    const float*  Af = (const float*)Avoid;
    const ushort* Ab = (const ushort*)Avoid;

    f32x4 pa[4];
    u32x4 pab[2];
    u32x4 pb;

    auto loadT = [&](int k0) {
        if (A_BF16) {
#pragma unroll
            for (int i = 0; i < 2; i++) {
                int s = tid + 256 * i; int row = s >> 2, c8 = s & 3;
                pab[i] = *(const u32x4*)(Ab + (m0 + row) * (long)K + k0 + c8 * 8);
            }
        } else {
#pragma unroll
            for (int i = 0; i < 4; i++) {
                int s = tid + 256 * i; int row = s >> 3, c4 = s & 7;
                const float* base = Af + (m0 + row) * (long)K + k0 + c4 * 4;
                f32x4 v = *(const f32x4*)base;
                if (NSUM > 0) {
#pragma unroll
                    for (int z = 1; z < NSUM; z++) v += *(const f32x4*)(base + z * pStride);
                }
                pa[i] = v;
            }
        }
        pb = *(const u32x4*)(B + (long)(k0 + bkr) * N + n0 + bcb * 8);
    };
    auto storeT = [&]() {
        if (A_BF16) {
#pragma unroll
            for (int i = 0; i < 2; i++) {
                int s = tid + 256 * i; int row = s >> 2, c8 = s & 3;
                *(u32x4*)(&As[row * 40 + c8 * 8]) = pab[i];
            }
        } else {
#pragma unroll
            for (int i = 0; i < 4; i++) {
                int s = tid + 256 * i; int row = s >> 3, c4 = s & 7;
                ushort4 w;
                w.x = f2bf(pa[i].x); w.y = f2bf(pa[i].y);
                w.z = f2bf(pa[i].z); w.w = f2bf(pa[i].w);
                *(ushort4*)(&As[row * 40 + c4 * 4]) = w;
            }
        }
        const ushort* p8 = (const ushort*)&pb;
#pragma unroll
        for (int j = 0; j < 8; j++) Bs[(bcb * 8 + j) * 40 + bkr] = p8[j];
    };

    f32x4 acc[4][2] = {};

    const int nk = (kend - kbeg) >> 5;
    loadT(kbeg);
    for (int t = 0; t < nk; ++t) {
        storeT();
        __syncthreads();
        if (t + 1 < nk) loadT(kbeg + ((t + 1) << 5));
        bf16x8 af[4], bfr[2];
#pragma unroll
        for (int fm = 0; fm < 4; fm++)
            af[fm] = *(const bf16x8*)(&As[(wr * 64 + fm * 16 + lr) * 40 + g * 8]);
#pragma unroll
        for (int fn = 0; fn < 2; fn++)
            bfr[fn] = *(const bf16x8*)(&Bs[(wc * 32 + fn * 16 + lr) * 40 + g * 8]);
#pragma unroll
        for (int fm = 0; fm < 4; fm++)
#pragma unroll
            for (int fn = 0; fn < 2; fn++)
                acc[fm][fn] = __builtin_amdgcn_mfma_f32_16x16x32_bf16(af[fm], bfr[fn], acc[fm][fn], 0, 0, 0);
        __syncthreads();
    }

    if (SPLIT) {
        float* P = Cf + (long)blockIdx.z * M * N;
#pragma unroll
        for (int fm = 0; fm < 4; fm++)
#pragma unroll
            for (int fn = 0; fn < 2; fn++)
#pragma unroll
                for (int rr = 0; rr < 4; rr++) {
                    long row = m0 + wr * 64 + fm * 16 + g * 4 + rr;
                    int  col = n0 + wc * 32 + fn * 16 + lr;
                    P[row * N + col] = acc[fm][fn][rr];
                }
    } else {
#pragma unroll
        for (int fm = 0; fm < 4; fm++)
#pragma unroll
            for (int fn = 0; fn < 2; fn++)
#pragma unroll
                for (int rr = 0; rr < 4; rr++) {
                    long row = m0 + wr * 64 + fm * 16 + g * 4 + rr;
                    int  col = n0 + wc * 32 + fn * 16 + lr;
                    float v = acc[fm][fn][rr];
                    if (HAS_BIAS) v += bias[col];
                    if (RELU) v = fmaxf(v, 0.f);
                    if (BF16_OUT) Cb[row * ldc + col] = f2bf(v);
                    else          Cf[row * ldc + col] = v;
                }
    }
}

// prep: A->bf16, X_n->bf16, W1/W2 transposes, Zt1 = X_e@W1h^T + b (bf16),
// zero stats. One launch, 10881 blocks.
__global__ __launch_bounds__(256) void prep_k(const float* __restrict__ A, ushort* __restrict__ Abf,
                                              const float* __restrict__ Xn, ushort* __restrict__ Xnb,
                                              const float* __restrict__ W1, ushort* __restrict__ W1t,
                                              const float* __restrict__ W2, ushort* __restrict__ W2t,
                                              const float* __restrict__ Xe, const float* __restrict__ Wh,
                                              const float* __restrict__ hb, ushort* __restrict__ Zt1,
                                              float* __restrict__ stats)
{
    int b = blockIdx.x, t = threadIdx.x;
    if (b < 8192) {                       // A: 16.78M elems, 8/thread
        long j = (long)b * 256 + t;
        f32x4 v0 = ((const f32x4*)A)[2 * j];
        f32x4 v1 = ((const f32x4*)A)[2 * j + 1];
        u32x4 w;
        w.x = pk2(v0.x, v0.y); w.y = pk2(v0.z, v0.w);
        w.z = pk2(v1.x, v1.y); w.w = pk2(v1.z, v1.w);
        ((u32x4*)Abf)[j] = w;
    } else if (b < 8448) {                // X_n
        long j = (long)(b - 8192) * 256 + t;
        f32x4 v0 = ((const f32x4*)Xn)[2 * j];
        f32x4 v1 = ((const f32x4*)Xn)[2 * j + 1];
        u32x4 w;
        w.x = pk2(v0.x, v0.y); w.y = pk2(v0.z, v0.w);
        w.z = pk2(v1.x, v1.y); w.w = pk2(v1.z, v1.w);
        ((u32x4*)Xnb)[j] = w;
    } else if (b < 8576) {                // W1 [256,128] -> T [128,256]
        int j = (b - 8448) * 256 + t;
        int i = j >> 8, o = j & 255;
        W1t[j] = f2bf(W1[o * 128 + i]);
    } else if (b < 8832) {                // W2 [256,256] -> T [256,256]
        int j = (b - 8576) * 256 + t;
        int i = j >> 8, o = j & 255;
        W2t[j] = f2bf(W2[o * 256 + i]);
    } else if (b < 10880) {               // Zt1[e][o] = X_e[e,:].Wh[o,:] + hb[o]
        int row = (b - 8832) * 4 + (t >> 6);
        int o   = t & 63;
        const float* xr = Xe + (long)row * 64;
        const float* wr = Wh + (long)o * 64;
        float acc = hb[o];
#pragma unroll 8
        for (int i = 0; i < 64; i++) acc += xr[i] * wr[i];
        Zt1[(long)row * 64 + o] = f2bf(acc);
    } else {
        if (t < 192) stats[t] = 0.f;      // gsum[64], gsq[64], S5[5]
    }
}

// fused: Zc1 = sum of 8 partials; column sum/sumsq stats. grid 256 x 256
__global__ __launch_bounds__(256) void bnred_k(const float* __restrict__ P,
                                               float* __restrict__ Zc,
                                               float* __restrict__ gsum, float* __restrict__ gsq)
{
    const long MN = 8192 * 64;
    int b = blockIdx.x, t = threadIdx.x;
    int c = t & 63, rg = t >> 6;
    float sx = 0.f, sq = 0.f;
    int base = b * 32 + rg;
#pragma unroll 4
    for (int i = 0; i < 8; i++) {
        long idx = (long)(base + 4 * i) * 64 + c;
        float x = 0.f;
#pragma unroll
        for (int z = 0; z < 8; z++) x += P[idx + z * MN];
        Zc[idx] = x;
        sx += x; sq += x * x;
    }
    __shared__ float ls[256], lq[256];
    ls[t] = sx; lq[t] = sq;
    __syncthreads();
    if (t < 64) {
        float a = ls[t] + ls[t + 64] + ls[t + 128] + ls[t + 192];
        float q = lq[t] + lq[t + 64] + lq[t + 128] + lq[t + 192];
        atomicAdd(&gsum[t], a);
        atomicAdd(&gsq[t], q);
    }
}

// Z1[row] = max_c relu(bn(Zc1[row,c])); wave per row, grid 2048 x 256
__global__ __launch_bounds__(256) void z1_k(const float* __restrict__ Zc,
                                            const float* __restrict__ gsum, const float* __restrict__ gsq,
                                            const float* __restrict__ g, const float* __restrict__ b,
                                            float* __restrict__ Z1)
{
    int w = threadIdx.x >> 6, lane = threadIdx.x & 63;
    int row = blockIdx.x * 4 + w;
    const float inv = 1.f / 8192.f;
    float m = gsum[lane] * inv;
    float v = gsq[lane] * inv - m * m;
    float x = Zc[row * 64 + lane];
    float y = fmaxf(g[lane] * (x - m) * rsqrtf(v + 1e-5f) + b[lane], 0.f);
#pragma unroll
    for (int o = 32; o > 0; o >>= 1) y = fmaxf(y, __shfl_xor(y, o));
    if (lane == 0) Z1[row] = y;
}

// s[i]=L1[i,:].Z1 ; r[i]=rowsum(L1[i,:]); block per row, grid 8192 x 256
__global__ __launch_bounds__(256) void pass2_k(const float* __restrict__ L1, const float* __restrict__ Z1,
                                               float* __restrict__ s, float* __restrict__ r)
{
    int row = blockIdx.x, t = threadIdx.x;
    int l = t & 63, w = t >> 6;
    const f32x4* rp = (const f32x4*)(L1 + (long)row * 8192);
    const f32x4* z4 = (const f32x4*)Z1;
    float as = 0.f, ar = 0.f;
#pragma unroll 4
    for (int k = 0; k < 8; k++) {
        f32x4 v = rp[t + 256 * k];
        f32x4 z = z4[t + 256 * k];
        as += v.x * z.x + v.y * z.y + v.z * z.z + v.w * z.w;
        ar += v.x + v.y + v.z + v.w;
    }
#pragma unroll
    for (int o = 32; o > 0; o >>= 1) { as += __shfl_xor(as, o); ar += __shfl_xor(ar, o); }
    __shared__ float sw[4], rw[4];
    if (l == 0) { sw[w] = as; rw[w] = ar; }
    __syncthreads();
    if (t == 0) {
        s[row] = sw[0] + sw[1] + sw[2] + sw[3];
        r[row] = rw[0] + rw[1] + rw[2] + rw[3];
    }
}

// single block (1024 thr): 5 moments of (s, r) over 8192 rows
__global__ __launch_bounds__(1024) void stats2_k(const float* __restrict__ s, const float* __restrict__ r,
                                                 float* __restrict__ S5)
{
    int t = threadIdx.x, l = t & 63, w = t >> 6;
    float Ss = 0, Sr = 0, Sss = 0, Srr = 0, Ssr = 0;
    for (int i = t; i < 8192; i += 1024) {
        float sv = s[i], rv = r[i];
        Ss += sv; Sr += rv; Sss += sv * sv; Srr += rv * rv; Ssr += sv * rv;
    }
#pragma unroll
    for (int o = 32; o > 0; o >>= 1) {
        Ss += __shfl_xor(Ss, o); Sr += __shfl_xor(Sr, o);
        Sss += __shfl_xor(Sss, o); Srr += __shfl_xor(Srr, o); Ssr += __shfl_xor(Ssr, o);
    }
    __shared__ float buf[16][5];
    if (l == 0) { buf[w][0] = Ss; buf[w][1] = Sr; buf[w][2] = Sss; buf[w][3] = Srr; buf[w][4] = Ssr; }
    __syncthreads();
    if (t < 5) {
        float a = 0.f;
#pragma unroll
        for (int i = 0; i < 16; i++) a += buf[i][t];
        S5[t] = a;
    }
}

// Z2 + edge_prob; wave per row; grid 2048 x 256
__global__ __launch_bounds__(256) void z2_edge_k(const float* __restrict__ s, const float* __restrict__ r,
                                                 const float* __restrict__ S,
                                                 const float* __restrict__ W2, const float* __restrict__ b2,
                                                 const float* __restrict__ g2, const float* __restrict__ bb2,
                                                 const float* __restrict__ eW, const float* __restrict__ eb,
                                                 const float* __restrict__ Z1,
                                                 float* __restrict__ Z2, float* __restrict__ edge_out)
{
    int w = threadIdx.x >> 6, lane = threadIdx.x & 63;
    int row = blockIdx.x * 4 + w;
    const float inv = 1.f / 8192.f;
    float ms = S[0] * inv, mr = S[1] * inv;
    float vs = S[2] * inv - ms * ms;
    float vr = S[3] * inv - mr * mr;
    float cv = S[4] * inv - ms * mr;
    float w2 = W2[lane], bz = b2[lane];
    float mc = w2 * ms + bz * mr;
    float vc = w2 * w2 * vs + 2.f * w2 * bz * cv + bz * bz * vr;
    float x  = w2 * s[row] + bz * r[row];
    float y  = fmaxf(g2[lane] * (x - mc) * rsqrtf(vc + 1e-5f) + bb2[lane], 0.f);
#pragma unroll
    for (int o = 32; o > 0; o >>= 1) y = fmaxf(y, __shfl_xor(y, o));
    if (lane == 0) {
        Z2[row] = y;
        float e = Z1[row] * eW[0] + y * eW[1] + eb[0];
        edge_out[row] = sigmoidf_(e);
    }
}

// H_e (B1@[Z1 Z2]) into hcat cols 256/257 + node head; block per row, grid 4096
__global__ __launch_bounds__(256) void he_node_k(const float* __restrict__ B1, const float* __restrict__ Z1,
                                                 const float* __restrict__ Z2, float* __restrict__ hcat,
                                                 const float* __restrict__ nW, const float* __restrict__ nb,
                                                 float* __restrict__ node_out)
{
    int n = blockIdx.x, t = threadIdx.x;
    int l = t & 63, w = t >> 6;
    const f32x4* rp  = (const f32x4*)(B1 + (long)n * 8192);
    const f32x4* z1v = (const f32x4*)Z1;
    const f32x4* z2v = (const f32x4*)Z2;
    float a1 = 0.f, a2 = 0.f;
#pragma unroll 4
    for (int k = 0; k < 8; k++) {
        f32x4 v = rp[t + 256 * k];
        f32x4 p = z1v[t + 256 * k];
        f32x4 q = z2v[t + 256 * k];
        a1 += v.x * p.x + v.y * p.y + v.z * p.z + v.w * p.w;
        a2 += v.x * q.x + v.y * q.y + v.z * q.z + v.w * q.w;
    }
    float d = hcat[(long)n * 258 + t] * nW[t];
#pragma unroll
    for (int o = 32; o > 0; o >>= 1) {
        a1 += __shfl_xor(a1, o); a2 += __shfl_xor(a2, o); d += __shfl_xor(d, o);
    }
    __shared__ float s1[4], s2[4], s3[4];
    if (l == 0) { s1[w] = a1; s2[w] = a2; s3[w] = d; }
    __syncthreads();
    if (t == 0) {
        float A1 = s1[0] + s1[1] + s1[2] + s1[3];
        float A2 = s2[0] + s2[1] + s2[2] + s2[3];
        float D  = s3[0] + s3[1] + s3[2] + s3[3];
        hcat[(long)n * 258 + 256] = A1;
        hcat[(long)n * 258 + 257] = A2;
        node_out[n] = sigmoidf_(D + A1 * nW[256] + A2 * nW[257] + nb[0]);
    }
}

// hyperedge gather-mean-dot-sigmoid; wave per hyperedge; grid 256 x 256
__global__ __launch_bounds__(256) void hyper_k(const void* __restrict__ he_idx,
                                               const float* __restrict__ hcat,
                                               const float* __restrict__ hW, const float* __restrict__ hb,
                                               float* __restrict__ out)
{
    int w = threadIdx.x >> 6, lane = threadIdx.x & 63;
    int h = blockIdx.x * 4 + w;
    const unsigned int* u = (const unsigned int*)he_idx;
    unsigned int odd = u[2 * lane + 1];
    bool is64 = __all(odd == 0u);
    float acc = 0.f;
    for (int k = 0; k < 8; k++) {
        int idx;
        if (is64) idx = (int)((const long long*)he_idx)[h * 8 + k];
        else      idx = ((const int*)he_idx)[h * 8 + k];
        const float* hr = hcat + (long)idx * 258;
        for (int d = lane; d < 258; d += 64) acc += hr[d] * hW[d];
    }
    acc *= 0.125f;
#pragma unroll
    for (int o = 32; o > 0; o >>= 1) acc += __shfl_xor(acc, o);
    if (lane == 0) out[h] = sigmoidf_(acc + hb[0]);
}

// ---------------------------------------------------------------------------
extern "C" void kernel_launch(void* const* d_in, const int* in_sizes, int n_in,
                              void* d_out, int out_size, void* d_ws, size_t ws_size,
                              hipStream_t stream)
{
    const float* X_n  = (const float*)d_in[0];
    const float* X_e  = (const float*)d_in[1];
    const float* A_t  = (const float*)d_in[2];
    const float* L1   = (const float*)d_in[3];
    const float* B1   = (const float*)d_in[4];
    const float* gW1  = (const float*)d_in[5];
    const float* gb1  = (const float*)d_in[6];
    const float* gW2  = (const float*)d_in[7];
    const float* gb2  = (const float*)d_in[8];
    const float* hW1  = (const float*)d_in[9];
    const float* hb1  = (const float*)d_in[10];
    const float* bn1g = (const float*)d_in[11];
    const float* bn1b = (const float*)d_in[12];
    const float* hW2  = (const float*)d_in[13];
    const float* hb2  = (const float*)d_in[14];
    const float* bn2g = (const float*)d_in[15];
    const float* bn2b = (const float*)d_in[16];
    const float* nW   = (const float*)d_in[17];
    const float* nb   = (const float*)d_in[18];
    const float* eW   = (const float*)d_in[19];
    const float* ebb  = (const float*)d_in[20];
    const float* yW   = (const float*)d_in[21];
    const float* yb   = (const float*)d_in[22];
    const void*  he   = d_in[23];

    float* out       = (float*)d_out;
    float* out_node  = out;              // 4096
    float* out_edge  = out + 4096;       // 8192
    float* out_hyper = out + 12288;      // 1024
    float* hcat      = out + 13312;      // 4096 x 258

    size_t off = 0;
    auto alloc = [&](size_t bytes) {
        void* p = (char*)d_ws + off;
        off = (off + bytes + 255) & ~(size_t)255;
        return p;
    };
    ushort* Abf   = (ushort*)alloc((size_t)4096 * 4096 * 2);  // 33.5 MB
    ushort* Xn_bf = (ushort*)alloc(4096 * 128 * 2);
    ushort* W1t   = (ushort*)alloc(128 * 256 * 2);
    ushort* W2t   = (ushort*)alloc(256 * 256 * 2);
    ushort* Zt1   = (ushort*)alloc(8192 * 64 * 2);
    float*  Zc1   = (float*)alloc(8192 * 64 * 4);
    float*  stats = (float*)alloc(256 * 4);   // gsum[64], gsq[64], S5[5]
    float*  gsum  = stats;
    float*  gsq   = stats + 64;
    float*  S5    = stats + 128;
    float*  Z1    = (float*)alloc(8192 * 4);
    float*  Z2    = (float*)alloc(8192 * 4);
    float*  sbuf  = (float*)alloc(8192 * 4);
    float*  rbuf  = (float*)alloc(8192 * 4);
    float*  P     = (float*)alloc((size_t)8192 * 64 * 8 * 4); // split-K partials (16.8 MB)

    // 1. prep: converts + transposes + Zt1 mini-GEMM + stat zero
    prep_k<<<10881, 256, 0, stream>>>(A_t, Abf, X_n, Xn_bf, gW1, W1t, gW2, W2t,
                                      X_e, hW1, hb1, Zt1, stats);

    // 2. K1: Abf @ Xnb -> P (split 4)
    gemm_kernel<0, true, true, false, false, false><<<dim3(32, 2, 4), 256, 0, stream>>>(
        Abf, Xn_bf, nullptr, P, nullptr, 4096, 128, 4096, 128, 1024, 0);
    // 3. K2: (sum P) @ W1t + b1, relu -> H_bf  (fused reduce)
    gemm_kernel<4, false, false, true, true, true><<<dim3(32, 4, 1), 256, 0, stream>>>(
        P, W1t, gb1, nullptr, (ushort*)Zc1 /*reuse as H_bf*/, 4096, 256, 128, 256, 0,
        (long)4096 * 128);
    ushort* H_bf = (ushort*)Zc1;  // 2 MB region reused before Zc1 is live
    // 4. K3: Abf @ H_bf -> P (split 2)
    gemm_kernel<0, true, true, false, false, false><<<dim3(32, 4, 2), 256, 0, stream>>>(
        Abf, H_bf, nullptr, P, nullptr, 4096, 256, 4096, 256, 2048, 0);
    // 5. K4: (sum P) @ W2t + b2, relu -> hcat (f32, ldc 258)  (fused reduce)
    gemm_kernel<2, false, false, true, false, true><<<dim3(32, 4, 1), 256, 0, stream>>>(
        P, W2t, gb2, hcat, nullptr, 4096, 256, 256, 258, 0, (long)4096 * 256);

    // 6. K6: L1(f32) @ Zt1 -> P (split 8)
    gemm_kernel<0, false, true, false, false, false><<<dim3(64, 1, 8), 256, 0, stream>>>(
        L1, Zt1, nullptr, P, nullptr, 8192, 64, 8192, 64, 1024, 0);
    // 7. bnred: Zc1 = sum P + column stats
    bnred_k<<<256, 256, 0, stream>>>(P, Zc1, gsum, gsq);
    // 8. z1
    z1_k<<<2048, 256, 0, stream>>>(Zc1, gsum, gsq, bn1g, bn1b, Z1);
    // 9. pass2
    pass2_k<<<8192, 256, 0, stream>>>(L1, Z1, sbuf, rbuf);
    // 10. stats2 (single block — avoids the same-line atomic train)
    stats2_k<<<1, 1024, 0, stream>>>(sbuf, rbuf, S5);
    // 11. z2 + edge head
    z2_edge_k<<<2048, 256, 0, stream>>>(sbuf, rbuf, S5, hW2, hb2, bn2g, bn2b,
                                        eW, ebb, Z1, Z2, out_edge);
    // 12. H_e + node head
    he_node_k<<<4096, 256, 0, stream>>>(B1, Z1, Z2, hcat, nW, nb, out_node);
    // 13. hyper head
    hyper_k<<<256, 256, 0, stream>>>(he, hcat, yW, yb, out_hyper);
}

// Round 8
// 291.551 us; speedup vs baseline: 2.6944x; 1.0419x over previous
//
#include <hip/hip_runtime.h>
#include <hip/hip_bf16.h>

using f32x4  = __attribute__((ext_vector_type(4))) float;
using u32x4  = __attribute__((ext_vector_type(4))) unsigned int;
using bf16x8 = __attribute__((ext_vector_type(8))) short;

__device__ __forceinline__ ushort f2bf(float x) {
    union { __hip_bfloat16 h; ushort u; } cv;
    cv.h = __float2bfloat16(x);
    return cv.u;
}
__device__ __forceinline__ unsigned pk2(float lo, float hi) {
    return (unsigned)f2bf(lo) | ((unsigned)f2bf(hi) << 16);
}
__device__ __forceinline__ float sigmoidf_(float x) { return 1.f / (1.f + expf(-x)); }

// ---------------------------------------------------------------------------
// GEMM body (device fn): C[M,N] = A * B(bf16,[K,N]) variants.
// A: bf16 | f32 | sum of NSUM f32 partial chunks (pStride apart), optionally
//    +abias[k] & relu (ABR) before bf16 conversion.
// BM=128, BN=64, BK=32; 4 waves (2x2), wave tile 64x32.
// ---------------------------------------------------------------------------
template<int NSUM, bool A_BF16, bool ABR, bool SPLIT, bool RELU, bool BF16_OUT, bool HAS_BIAS>
__device__ __forceinline__ void gemm_body(
    ushort* As, ushort* Bs,
    const void* __restrict__ Avoid, const ushort* __restrict__ B,
    const float* __restrict__ abias, const float* __restrict__ bias,
    float* __restrict__ Cf, ushort* __restrict__ Cb,
    int M, int N, int K, int ldc, int kPerChunk, long pStride,
    int bx, int by, int bz)
{
    const int tid  = threadIdx.x;
    const int lane = tid & 63;
    const int wid  = tid >> 6;
    const int wr   = wid >> 1, wc = wid & 1;
    const int g    = lane >> 4, lr = lane & 15;
    const long m0  = (long)bx * 128;
    const int  n0  = by * 64;

    int kbeg = 0, kend = K;
    if (SPLIT) { kbeg = bz * kPerChunk; kend = kbeg + kPerChunk; if (kend > K) kend = K; }

    const int bkr = tid & 31;
    const int bcb = tid >> 5;

    const float*  Af = (const float*)Avoid;
    const ushort* Ab = (const ushort*)Avoid;

    f32x4 pa[4];
    u32x4 pab[2];
    u32x4 pb;

    auto loadT = [&](int k0) {
        if (A_BF16) {
#pragma unroll
            for (int i = 0; i < 2; i++) {
                int s = tid + 256 * i; int row = s >> 2, c8 = s & 3;
                pab[i] = *(const u32x4*)(Ab + (m0 + row) * (long)K + k0 + c8 * 8);
            }
        } else {
#pragma unroll
            for (int i = 0; i < 4; i++) {
                int s = tid + 256 * i; int row = s >> 3, c4 = s & 7;
                const float* base = Af + (m0 + row) * (long)K + k0 + c4 * 4;
                f32x4 v = *(const f32x4*)base;
                if (NSUM > 0) {
#pragma unroll
                    for (int z = 1; z < NSUM; z++) v += *(const f32x4*)(base + z * pStride);
                }
                if (ABR) {
                    f32x4 bq = *(const f32x4*)(abias + k0 + c4 * 4);
                    v.x = fmaxf(v.x + bq.x, 0.f);
                    v.y = fmaxf(v.y + bq.y, 0.f);
                    v.z = fmaxf(v.z + bq.z, 0.f);
                    v.w = fmaxf(v.w + bq.w, 0.f);
                }
                pa[i] = v;
            }
        }
        pb = *(const u32x4*)(B + (long)(k0 + bkr) * N + n0 + bcb * 8);
    };
    auto storeT = [&]() {
        if (A_BF16) {
#pragma unroll
            for (int i = 0; i < 2; i++) {
                int s = tid + 256 * i; int row = s >> 2, c8 = s & 3;
                *(u32x4*)(&As[row * 40 + c8 * 8]) = pab[i];
            }
        } else {
#pragma unroll
            for (int i = 0; i < 4; i++) {
                int s = tid + 256 * i; int row = s >> 3, c4 = s & 7;
                ushort4 w;
                w.x = f2bf(pa[i].x); w.y = f2bf(pa[i].y);
                w.z = f2bf(pa[i].z); w.w = f2bf(pa[i].w);
                *(ushort4*)(&As[row * 40 + c4 * 4]) = w;
            }
        }
        const ushort* p8 = (const ushort*)&pb;
#pragma unroll
        for (int j = 0; j < 8; j++) Bs[(bcb * 8 + j) * 40 + bkr] = p8[j];
    };

    f32x4 acc[4][2] = {};

    const int nk = (kend - kbeg) >> 5;
    loadT(kbeg);
    for (int t = 0; t < nk; ++t) {
        storeT();
        __syncthreads();
        if (t + 1 < nk) loadT(kbeg + ((t + 1) << 5));
        bf16x8 af[4], bfr[2];
#pragma unroll
        for (int fm = 0; fm < 4; fm++)
            af[fm] = *(const bf16x8*)(&As[(wr * 64 + fm * 16 + lr) * 40 + g * 8]);
#pragma unroll
        for (int fn = 0; fn < 2; fn++)
            bfr[fn] = *(const bf16x8*)(&Bs[(wc * 32 + fn * 16 + lr) * 40 + g * 8]);
#pragma unroll
        for (int fm = 0; fm < 4; fm++)
#pragma unroll
            for (int fn = 0; fn < 2; fn++)
                acc[fm][fn] = __builtin_amdgcn_mfma_f32_16x16x32_bf16(af[fm], bfr[fn], acc[fm][fn], 0, 0, 0);
        __syncthreads();
    }

    if (SPLIT) {
        float* P = Cf + (long)bz * M * N;
#pragma unroll
        for (int fm = 0; fm < 4; fm++)
#pragma unroll
            for (int fn = 0; fn < 2; fn++)
#pragma unroll
                for (int rr = 0; rr < 4; rr++) {
                    long row = m0 + wr * 64 + fm * 16 + g * 4 + rr;
                    int  col = n0 + wc * 32 + fn * 16 + lr;
                    P[row * N + col] = acc[fm][fn][rr];
                }
    } else {
#pragma unroll
        for (int fm = 0; fm < 4; fm++)
#pragma unroll
            for (int fn = 0; fn < 2; fn++)
#pragma unroll
                for (int rr = 0; rr < 4; rr++) {
                    long row = m0 + wr * 64 + fm * 16 + g * 4 + rr;
                    int  col = n0 + wc * 32 + fn * 16 + lr;
                    float v = acc[fm][fn][rr];
                    if (HAS_BIAS) v += bias[col];
                    if (RELU) v = fmaxf(v, 0.f);
                    if (BF16_OUT) Cb[row * ldc + col] = f2bf(v);
                    else          Cf[row * ldc + col] = v;
                }
    }
}

// ---------------------------------------------------------------------------
// 1. prep: A->bf16 | T1 = Xn@W1^T (bf16) | Zt1 = Xe@Wh^T + hb (bf16) |
//    W2 transpose (bf16) | zero stats.  11009 blocks.
// ---------------------------------------------------------------------------
__global__ __launch_bounds__(256)
void prep_k(const float* __restrict__ A, ushort* __restrict__ Abf,
            const float* __restrict__ Xn, const float* __restrict__ W1, ushort* __restrict__ T1,
            const float* __restrict__ Xe, const float* __restrict__ Wh,
            const float* __restrict__ hb, ushort* __restrict__ Zt1,
            const float* __restrict__ W2, ushort* __restrict__ W2t,
            float* __restrict__ stats)
{
    __shared__ float xs[1024];
    int b = blockIdx.x, t = threadIdx.x;
    if (b < 8192) {                       // A convert, 8 elems/thread
        long j = (long)b * 256 + t;
        f32x4 v0 = ((const f32x4*)A)[2 * j];
        f32x4 v1 = ((const f32x4*)A)[2 * j + 1];
        u32x4 w;
        w.x = pk2(v0.x, v0.y); w.y = pk2(v0.z, v0.w);
        w.z = pk2(v1.x, v1.y); w.w = pk2(v1.z, v1.w);
        ((u32x4*)Abf)[j] = w;
    } else if (b < 8704) {                // T1: 8 rows per block, thread = out col
        int r0 = (b - 8192) * 8;
        for (int idx = t; idx < 1024; idx += 256) xs[idx] = Xn[(long)r0 * 128 + idx];
        __syncthreads();
        float acc[8] = {};
        const float* wrow = W1 + (long)t * 128;
        for (int i = 0; i < 128; i++) {
            float w = wrow[i];
#pragma unroll
            for (int r = 0; r < 8; r++) acc[r] += xs[r * 128 + i] * w;
        }
#pragma unroll
        for (int r = 0; r < 8; r++) T1[(long)(r0 + r) * 256 + t] = f2bf(acc[r]);
    } else if (b < 10752) {               // Zt1: 4 rows/block, wave per row
        int row = (b - 8704) * 4 + (t >> 6);
        int o   = t & 63;
        const float* xr = Xe + (long)row * 64;
        const float* wr = Wh + (long)o * 64;
        float acc = hb[o];
#pragma unroll 8
        for (int i = 0; i < 64; i++) acc += xr[i] * wr[i];
        Zt1[(long)row * 64 + o] = f2bf(acc);
    } else if (b < 11008) {               // W2 [256,256] -> T
        int j = (b - 10752) * 256 + t;
        int i = j >> 8, o = j & 255;
        W2t[j] = f2bf(W2[o * 256 + i]);
    } else {
        if (t < 256) stats[t] = 0.f;
    }
}

// ---------------------------------------------------------------------------
// device bodies for merged light kernels
// ---------------------------------------------------------------------------
__device__ __forceinline__ void bnred_body(int b, const float* __restrict__ P,
                                           float* __restrict__ Zc,
                                           float* __restrict__ gsum, float* __restrict__ gsq)
{
    const long MN = 8192 * 64;
    int t = threadIdx.x;
    int c = t & 63, rg = t >> 6;
    float sx = 0.f, sq = 0.f;
    int base = b * 32 + rg;
#pragma unroll 4
    for (int i = 0; i < 8; i++) {
        long idx = (long)(base + 4 * i) * 64 + c;
        float x = 0.f;
#pragma unroll
        for (int z = 0; z < 8; z++) x += P[idx + z * MN];
        Zc[idx] = x;
        sx += x; sq += x * x;
    }
    __shared__ float ls[256], lq[256];
    ls[t] = sx; lq[t] = sq;
    __syncthreads();
    if (t < 64) {
        float a = ls[t] + ls[t + 64] + ls[t + 128] + ls[t + 192];
        float q = lq[t] + lq[t + 64] + lq[t + 128] + lq[t + 192];
        atomicAdd(&gsum[t], a);
        atomicAdd(&gsq[t], q);
    }
}

__device__ __forceinline__ void z1_body(int b, const float* __restrict__ Zc,
                                        const float* __restrict__ gsum, const float* __restrict__ gsq,
                                        const float* __restrict__ g, const float* __restrict__ bb,
                                        float* __restrict__ Z1)
{
    int w = threadIdx.x >> 6, lane = threadIdx.x & 63;
    int row = b * 4 + w;
    const float inv = 1.f / 8192.f;
    float m = gsum[lane] * inv;
    float v = gsq[lane] * inv - m * m;
    float x = Zc[row * 64 + lane];
    float y = fmaxf(g[lane] * (x - m) * rsqrtf(v + 1e-5f) + bb[lane], 0.f);
#pragma unroll
    for (int o = 32; o > 0; o >>= 1) y = fmaxf(y, __shfl_xor(y, o));
    if (lane == 0) Z1[row] = y;
}

__device__ __forceinline__ void pass2_body(int row, const float* __restrict__ L1,
                                           const float* __restrict__ Z1,
                                           float* __restrict__ s, float* __restrict__ r)
{
    int t = threadIdx.x;
    int l = t & 63, w = t >> 6;
    const f32x4* rp = (const f32x4*)(L1 + (long)row * 8192);
    const f32x4* z4 = (const f32x4*)Z1;
    float as = 0.f, ar = 0.f;
#pragma unroll 4
    for (int k = 0; k < 8; k++) {
        f32x4 v = rp[t + 256 * k];
        f32x4 z = z4[t + 256 * k];
        as += v.x * z.x + v.y * z.y + v.z * z.z + v.w * z.w;
        ar += v.x + v.y + v.z + v.w;
    }
#pragma unroll
    for (int o = 32; o > 0; o >>= 1) { as += __shfl_xor(as, o); ar += __shfl_xor(ar, o); }
    __shared__ float sw[4], rw[4];
    if (l == 0) { sw[w] = as; rw[w] = ar; }
    __syncthreads();
    if (t == 0) {
        s[row] = sw[0] + sw[1] + sw[2] + sw[3];
        r[row] = rw[0] + rw[1] + rw[2] + rw[3];
    }
}

// hcat reduce: hcat[:, 0:256] = relu(sum_z P2 + b2); 1024 blocks
__device__ __forceinline__ void hcatred_body(int b, const float* __restrict__ P2,
                                             const float* __restrict__ b2, float* __restrict__ hcat)
{
    const long MNq = (long)4096 * 256 / 4;
    int j = b * 256 + threadIdx.x;        // quad index, 262144 total
    int row = j >> 6, c4 = (j & 63) * 4;
    const f32x4* Q = (const f32x4*)P2;
    f32x4 v = Q[j] + Q[j + MNq] + Q[j + 2 * MNq] + Q[j + 3 * MNq];
    f32x4 bq = *(const f32x4*)(b2 + c4);
    float* dst = hcat + (long)row * 258 + c4;
    float2 lo = { fmaxf(v.x + bq.x, 0.f), fmaxf(v.y + bq.y, 0.f) };
    float2 hi = { fmaxf(v.z + bq.z, 0.f), fmaxf(v.w + bq.w, 0.f) };
    *(float2*)dst = lo;
    *(float2*)(dst + 2) = hi;
}

// ---------------------------------------------------------------------------
// merged launches
// ---------------------------------------------------------------------------
// dual_a: [0,512) K6: L1@Zt1 split8 -> Pa ; [512,1024) K1': Abf@T1 split4 -> Pb
__global__ __launch_bounds__(256)
void dual_a_k(const float* __restrict__ L1, const ushort* __restrict__ Zt1, float* __restrict__ Pa,
              const ushort* __restrict__ Abf, const ushort* __restrict__ T1, float* __restrict__ Pb)
{
    __shared__ ushort As[128 * 40];
    __shared__ ushort Bs[64 * 40];
    int bid = blockIdx.x;
    if (bid < 512) {
        gemm_body<0, false, false, true, false, false, false>(
            As, Bs, L1, Zt1, nullptr, nullptr, Pa, nullptr,
            8192, 64, 8192, 64, 1024, 0, bid & 63, 0, bid >> 6);
    } else {
        int b = bid - 512;
        gemm_body<0, true, false, true, false, false, false>(
            As, Bs, Abf, T1, nullptr, nullptr, Pb, nullptr,
            4096, 256, 4096, 256, 1024, 0, b & 31, (b >> 5) & 3, b >> 7);
    }
}

// dual_b: [0,128) T2 = relu(sum Pb + b1) @ W2t -> T2 bf16 ; [128,384) bnred
__global__ __launch_bounds__(256)
void dual_b_k(const float* __restrict__ Pb, const float* __restrict__ gb1,
              const ushort* __restrict__ W2t, ushort* __restrict__ T2,
              const float* __restrict__ Pa, float* __restrict__ Zc1,
              float* __restrict__ gsum, float* __restrict__ gsq)
{
    __shared__ ushort As[128 * 40];
    __shared__ ushort Bs[64 * 40];
    int bid = blockIdx.x;
    if (bid < 128) {
        gemm_body<4, false, true, false, false, true, false>(
            As, Bs, Pb, W2t, gb1, nullptr, nullptr, T2,
            4096, 256, 256, 256, 0, (long)4096 * 256, bid & 31, bid >> 5, 0);
    } else {
        bnred_body(bid - 128, Pa, Zc1, gsum, gsq);
    }
}

// dual_c: [0,512) K2': Abf@T2 split4 -> Pa ; [512,2560) z1
__global__ __launch_bounds__(256)
void dual_c_k(const ushort* __restrict__ Abf, const ushort* __restrict__ T2, float* __restrict__ Pa,
              const float* __restrict__ Zc1, const float* __restrict__ gsum,
              const float* __restrict__ gsq, const float* __restrict__ bn1g,
              const float* __restrict__ bn1b, float* __restrict__ Z1)
{
    __shared__ ushort As[128 * 40];
    __shared__ ushort Bs[64 * 40];
    int bid = blockIdx.x;
    if (bid < 512) {
        gemm_body<0, true, false, true, false, false, false>(
            As, Bs, Abf, T2, nullptr, nullptr, Pa, nullptr,
            4096, 256, 4096, 256, 1024, 0, bid & 31, (bid >> 5) & 3, bid >> 7);
    } else {
        z1_body(bid - 512, Zc1, gsum, gsq, bn1g, bn1b, Z1);
    }
}

// dual_d: [0,1024) hcat reduce ; [1024,9216) pass2
__global__ __launch_bounds__(256)
void dual_d_k(const float* __restrict__ Pa, const float* __restrict__ gb2, float* __restrict__ hcat,
              const float* __restrict__ L1, const float* __restrict__ Z1,
              float* __restrict__ s, float* __restrict__ r)
{
    int bid = blockIdx.x;
    if (bid < 1024) hcatred_body(bid, Pa, gb2, hcat);
    else            pass2_body(bid - 1024, L1, Z1, s, r);
}

// single block (1024 thr): 5 moments of (s, r) over 8192 rows
__global__ __launch_bounds__(1024) void stats2_k(const float* __restrict__ s, const float* __restrict__ r,
                                                 float* __restrict__ S5)
{
    int t = threadIdx.x, l = t & 63, w = t >> 6;
    float Ss = 0, Sr = 0, Sss = 0, Srr = 0, Ssr = 0;
    for (int i = t; i < 8192; i += 1024) {
        float sv = s[i], rv = r[i];
        Ss += sv; Sr += rv; Sss += sv * sv; Srr += rv * rv; Ssr += sv * rv;
    }
#pragma unroll
    for (int o = 32; o > 0; o >>= 1) {
        Ss += __shfl_xor(Ss, o); Sr += __shfl_xor(Sr, o);
        Sss += __shfl_xor(Sss, o); Srr += __shfl_xor(Srr, o); Ssr += __shfl_xor(Ssr, o);
    }
    __shared__ float buf[16][5];
    if (l == 0) { buf[w][0] = Ss; buf[w][1] = Sr; buf[w][2] = Sss; buf[w][3] = Srr; buf[w][4] = Ssr; }
    __syncthreads();
    if (t < 5) {
        float a = 0.f;
#pragma unroll
        for (int i = 0; i < 16; i++) a += buf[i][t];
        S5[t] = a;
    }
}

// Z2 + edge_prob; wave per row; grid 2048 x 256
__global__ __launch_bounds__(256) void z2_edge_k(const float* __restrict__ s, const float* __restrict__ r,
                                                 const float* __restrict__ S,
                                                 const float* __restrict__ W2, const float* __restrict__ b2,
                                                 const float* __restrict__ g2, const float* __restrict__ bb2,
                                                 const float* __restrict__ eW, const float* __restrict__ eb,
                                                 const float* __restrict__ Z1,
                                                 float* __restrict__ Z2, float* __restrict__ edge_out)
{
    int w = threadIdx.x >> 6, lane = threadIdx.x & 63;
    int row = blockIdx.x * 4 + w;
    const float inv = 1.f / 8192.f;
    float ms = S[0] * inv, mr = S[1] * inv;
    float vs = S[2] * inv - ms * ms;
    float vr = S[3] * inv - mr * mr;
    float cv = S[4] * inv - ms * mr;
    float w2 = W2[lane], bz = b2[lane];
    float mc = w2 * ms + bz * mr;
    float vc = w2 * w2 * vs + 2.f * w2 * bz * cv + bz * bz * vr;
    float x  = w2 * s[row] + bz * r[row];
    float y  = fmaxf(g2[lane] * (x - mc) * rsqrtf(vc + 1e-5f) + bb2[lane], 0.f);
#pragma unroll
    for (int o = 32; o > 0; o >>= 1) y = fmaxf(y, __shfl_xor(y, o));
    if (lane == 0) {
        Z2[row] = y;
        float e = Z1[row] * eW[0] + y * eW[1] + eb[0];
        edge_out[row] = sigmoidf_(e);
    }
}

// H_e (B1@[Z1 Z2]) into hcat cols 256/257 + node head; block per row, grid 4096
__global__ __launch_bounds__(256) void he_node_k(const float* __restrict__ B1, const float* __restrict__ Z1,
                                                 const float* __restrict__ Z2, float* __restrict__ hcat,
                                                 const float* __restrict__ nW, const float* __restrict__ nb,
                                                 float* __restrict__ node_out)
{
    int n = blockIdx.x, t = threadIdx.x;
    int l = t & 63, w = t >> 6;
    const f32x4* rp  = (const f32x4*)(B1 + (long)n * 8192);
    const f32x4* z1v = (const f32x4*)Z1;
    const f32x4* z2v = (const f32x4*)Z2;
    float a1 = 0.f, a2 = 0.f;
#pragma unroll 4
    for (int k = 0; k < 8; k++) {
        f32x4 v = rp[t + 256 * k];
        f32x4 p = z1v[t + 256 * k];
        f32x4 q = z2v[t + 256 * k];
        a1 += v.x * p.x + v.y * p.y + v.z * p.z + v.w * p.w;
        a2 += v.x * q.x + v.y * q.y + v.z * q.z + v.w * q.w;
    }
    float d = hcat[(long)n * 258 + t] * nW[t];
#pragma unroll
    for (int o = 32; o > 0; o >>= 1) {
        a1 += __shfl_xor(a1, o); a2 += __shfl_xor(a2, o); d += __shfl_xor(d, o);
    }
    __shared__ float s1[4], s2[4], s3[4];
    if (l == 0) { s1[w] = a1; s2[w] = a2; s3[w] = d; }
    __syncthreads();
    if (t == 0) {
        float A1 = s1[0] + s1[1] + s1[2] + s1[3];
        float A2 = s2[0] + s2[1] + s2[2] + s2[3];
        float D  = s3[0] + s3[1] + s3[2] + s3[3];
        hcat[(long)n * 258 + 256] = A1;
        hcat[(long)n * 258 + 257] = A2;
        node_out[n] = sigmoidf_(D + A1 * nW[256] + A2 * nW[257] + nb[0]);
    }
}

// hyperedge gather-mean-dot-sigmoid; wave per hyperedge; grid 256 x 256
__global__ __launch_bounds__(256) void hyper_k(const void* __restrict__ he_idx,
                                               const float* __restrict__ hcat,
                                               const float* __restrict__ hW, const float* __restrict__ hb,
                                               float* __restrict__ out)
{
    int w = threadIdx.x >> 6, lane = threadIdx.x & 63;
    int h = blockIdx.x * 4 + w;
    const unsigned int* u = (const unsigned int*)he_idx;
    unsigned int odd = u[2 * lane + 1];
    bool is64 = __all(odd == 0u);
    float acc = 0.f;
    for (int k = 0; k < 8; k++) {
        int idx;
        if (is64) idx = (int)((const long long*)he_idx)[h * 8 + k];
        else      idx = ((const int*)he_idx)[h * 8 + k];
        const float* hr = hcat + (long)idx * 258;
        for (int d = lane; d < 258; d += 64) acc += hr[d] * hW[d];
    }
    acc *= 0.125f;
#pragma unroll
    for (int o = 32; o > 0; o >>= 1) acc += __shfl_xor(acc, o);
    if (lane == 0) out[h] = sigmoidf_(acc + hb[0]);
}

// ---------------------------------------------------------------------------
extern "C" void kernel_launch(void* const* d_in, const int* in_sizes, int n_in,
                              void* d_out, int out_size, void* d_ws, size_t ws_size,
                              hipStream_t stream)
{
    const float* X_n  = (const float*)d_in[0];
    const float* X_e  = (const float*)d_in[1];
    const float* A_t  = (const float*)d_in[2];
    const float* L1   = (const float*)d_in[3];
    const float* B1   = (const float*)d_in[4];
    const float* gW1  = (const float*)d_in[5];
    const float* gb1  = (const float*)d_in[6];
    const float* gW2  = (const float*)d_in[7];
    const float* gb2  = (const float*)d_in[8];
    const float* hW1  = (const float*)d_in[9];
    const float* hb1  = (const float*)d_in[10];
    const float* bn1g = (const float*)d_in[11];
    const float* bn1b = (const float*)d_in[12];
    const float* hW2  = (const float*)d_in[13];
    const float* hb2  = (const float*)d_in[14];
    const float* bn2g = (const float*)d_in[15];
    const float* bn2b = (const float*)d_in[16];
    const float* nW   = (const float*)d_in[17];
    const float* nb   = (const float*)d_in[18];
    const float* eW   = (const float*)d_in[19];
    const float* ebb  = (const float*)d_in[20];
    const float* yW   = (const float*)d_in[21];
    const float* yb   = (const float*)d_in[22];
    const void*  he   = d_in[23];

    float* out       = (float*)d_out;
    float* out_node  = out;              // 4096
    float* out_edge  = out + 4096;       // 8192
    float* out_hyper = out + 12288;      // 1024
    float* hcat      = out + 13312;      // 4096 x 258

    size_t off = 0;
    auto alloc = [&](size_t bytes) {
        void* p = (char*)d_ws + off;
        off = (off + bytes + 255) & ~(size_t)255;
        return p;
    };
    ushort* Abf   = (ushort*)alloc((size_t)4096 * 4096 * 2);  // 33.5 MB
    ushort* T1    = (ushort*)alloc(4096 * 256 * 2);
    ushort* T2    = (ushort*)alloc(4096 * 256 * 2);
    ushort* Zt1   = (ushort*)alloc(8192 * 64 * 2);
    ushort* W2t   = (ushort*)alloc(256 * 256 * 2);
    float*  Zc1   = (float*)alloc(8192 * 64 * 4);
    float*  stats = (float*)alloc(256 * 4);   // gsum[64], gsq[64], S5[5], ...
    float*  gsum  = stats;
    float*  gsq   = stats + 64;
    float*  S5    = stats + 128;
    float*  Z1    = (float*)alloc(8192 * 4);
    float*  Z2    = (float*)alloc(8192 * 4);
    float*  sbuf  = (float*)alloc(8192 * 4);
    float*  rbuf  = (float*)alloc(8192 * 4);
    float*  Pa    = (float*)alloc((size_t)8192 * 64 * 8 * 4); // 16.8 MB (K6 z8 / K2' z4)
    float*  Pb    = (float*)alloc((size_t)4096 * 256 * 4 * 4); // 16.8 MB (K1' z4)

    // 1. prep: A convert + T1 + Zt1 + W2t + stats zero
    prep_k<<<11009, 256, 0, stream>>>(A_t, Abf, X_n, gW1, T1, X_e, hW1, hb1, Zt1,
                                      gW2, W2t, stats);

    // 2. dual_a: {L1@Zt1 -> Pa} || {Abf@T1 -> Pb}
    dual_a_k<<<1024, 256, 0, stream>>>(L1, Zt1, Pa, Abf, T1, Pb);

    // 3. dual_b: {T2 = relu(sum Pb + b1)@W2t} || {bnred: Zc1 + stats}
    dual_b_k<<<384, 256, 0, stream>>>(Pb, gb1, W2t, T2, Pa, Zc1, gsum, gsq);

    // 4. dual_c: {Abf@T2 -> Pa} || {z1}
    dual_c_k<<<2560, 256, 0, stream>>>(Abf, T2, Pa, Zc1, gsum, gsq, bn1g, bn1b, Z1);

    // 5. dual_d: {hcat = relu(sum Pa + b2)} || {pass2: s, r}
    dual_d_k<<<9216, 256, 0, stream>>>(Pa, gb2, hcat, L1, Z1, sbuf, rbuf);

    // 6. stats2 (single block)
    stats2_k<<<1, 1024, 0, stream>>>(sbuf, rbuf, S5);

    // 7. z2 + edge head
    z2_edge_k<<<2048, 256, 0, stream>>>(sbuf, rbuf, S5, hW2, hb2, bn2g, bn2b,
                                        eW, ebb, Z1, Z2, out_edge);

    // 8. H_e + node head
    he_node_k<<<4096, 256, 0, stream>>>(B1, Z1, Z2, hcat, nW, nb, out_node);

    // 9. hyper head
    hyper_k<<<256, 256, 0, stream>>>(he, hcat, yW, yb, out_hyper);
}